// Round 1
// baseline (302.006 us; speedup 1.0000x reference)
//
#include <hip/hip_runtime.h>
#include <hip/hip_bf16.h>
#include <cstdint>

// Problem constants: B=1, C=256, F=8, H=32, W=32 -> N = 8192 spatial, 2M elements.
#define NSP 8192
#define CCH 256

typedef __attribute__((ext_vector_type(4))) float f32x4;
typedef __attribute__((ext_vector_type(8))) short bf16x8;

__device__ __forceinline__ ushort f2bf(float f) {
  union { float f; uint32_t u; } v; v.f = f;
  uint32_t r = (v.u + 0x7FFFu + ((v.u >> 16) & 1u)) >> 16;
  return (ushort)r;
}

// global -> LDS direct copy, 16B per lane. LDS dest must be wave-uniform base.
__device__ __forceinline__ void gload_lds16(const void* g, void* l) {
  auto gp = (const __attribute__((address_space(1))) uint32_t*)(uintptr_t)g;
  auto lp = (__attribute__((address_space(3))) uint32_t*)(uint32_t)(uintptr_t)l;
  __builtin_amdgcn_global_load_lds(gp, lp, 16, 0, 0);
}

// ---------------- K1a: per-block partial sum/sumsq over x (2M floats) -------
__global__ __launch_bounds__(256) void k_stats1(const float* __restrict__ x,
                                                float* __restrict__ part) {
  int t = threadIdx.x, b = blockIdx.x;
  float s = 0.f, ss = 0.f;
  const float4* x4 = (const float4*)x;
  for (int i = 0; i < 4; ++i) {
    float4 v = x4[(size_t)i * 131072 + b * 256 + t];
    s += v.x + v.y + v.z + v.w;
    ss += v.x * v.x + v.y * v.y + v.z * v.z + v.w * v.w;
  }
  for (int m = 1; m < 64; m <<= 1) { s += __shfl_xor(s, m); ss += __shfl_xor(ss, m); }
  __shared__ float ls[4], lss[4];
  int w = t >> 6, lane = t & 63;
  if (lane == 0) { ls[w] = s; lss[w] = ss; }
  __syncthreads();
  if (t == 0) {
    part[b * 2 + 0] = ls[0] + ls[1] + ls[2] + ls[3];
    part[b * 2 + 1] = lss[0] + lss[1] + lss[2] + lss[3];
  }
}

// ---------------- K1b: finalize mean / rsqrt(var+eps) ----------------------
__global__ __launch_bounds__(256) void k_stats2(const float* __restrict__ part,
                                                float* __restrict__ stat) {
  int t = threadIdx.x;
  float s = 0.f, ss = 0.f;
  for (int i = t; i < 512; i += 256) { s += part[i * 2]; ss += part[i * 2 + 1]; }
  for (int m = 1; m < 64; m <<= 1) { s += __shfl_xor(s, m); ss += __shfl_xor(ss, m); }
  __shared__ float ls[4], lss[4];
  int w = t >> 6, lane = t & 63;
  if (lane == 0) { ls[w] = s; lss[w] = ss; }
  __syncthreads();
  if (t == 0) {
    float sum = ls[0] + ls[1] + ls[2] + ls[3];
    float ssum = lss[0] + lss[1] + lss[2] + lss[3];
    float mean = sum * (1.f / 2097152.f);
    float var = ssum * (1.f / 2097152.f) - mean * mean;
    stat[0] = mean;
    stat[1] = rsqrtf(var + 1e-5f);
  }
}

// ---------------- K2a: cast weights to bf16 ---------------------------------
__global__ __launch_bounds__(256) void k_castw(const float* __restrict__ qw, const float* __restrict__ kw,
                                               const float* __restrict__ vw, const float* __restrict__ ow,
                                               ushort* __restrict__ wqkv, ushort* __restrict__ wo) {
  int idx = blockIdx.x * 256 + threadIdx.x;  // grid 1024 -> 262144
  if (idx < 65536) wqkv[idx] = f2bf(qw[idx]);
  else if (idx < 131072) wqkv[idx] = f2bf(kw[idx - 65536]);
  else if (idx < 196608) wqkv[idx] = f2bf(vw[idx - 131072]);
  else wo[idx - 196608] = f2bf(ow[idx - 196608]);
}

// ---------------- K2b: normalize + transpose -> xnT bf16 [8192][256] --------
__global__ __launch_bounds__(256) void k_norm_t(const float* __restrict__ x,
                                                const float* __restrict__ gw, const float* __restrict__ gb,
                                                const float* __restrict__ stat, ushort* __restrict__ xnT) {
  __shared__ float tile[64][66];
  int n0 = blockIdx.x * 64, c0 = blockIdx.y * 64;
  int t = threadIdx.x, colr = t & 63, rq = t >> 6;
  float mean = stat[0], rinv = stat[1];
  for (int rr = 0; rr < 16; ++rr) {
    int row = rr * 4 + rq;  // c-local
    int c = c0 + row;
    float v = x[(size_t)c * NSP + n0 + colr];
    tile[row][colr] = (v - mean) * rinv * gw[c] + gb[c];
  }
  __syncthreads();
  for (int rr = 0; rr < 16; ++rr) {
    int rowW = rr * 4 + rq;  // n-local
    xnT[(size_t)(n0 + rowW) * 256 + c0 + colr] = f2bf(tile[colr][rowW]);
  }
}

// ---------------- K3: QKV GEMM -> qT(scaled)/kT/vT [8192][256] bf16 ---------
__global__ __launch_bounds__(256) void k_qkv(const ushort* __restrict__ xnT, const ushort* __restrict__ wqkv,
                                             const float* __restrict__ qb, const float* __restrict__ kb,
                                             const float* __restrict__ vb,
                                             ushort* __restrict__ qT, ushort* __restrict__ kT,
                                             ushort* __restrict__ vT) {
  int nb = blockIdx.x, ob = blockIdx.y;
  int w = threadIdx.x >> 6, lane = threadIdx.x & 63;
  int l16 = lane & 15, kgrp = lane >> 4;
  int n_row = nb * 64 + w * 16 + l16;
  bf16x8 a[8];
  const bf16x8* arow = (const bf16x8*)(xnT + (size_t)n_row * 256);
  for (int ks = 0; ks < 8; ++ks) a[ks] = arow[ks * 4 + kgrp];
  f32x4 acc[4];
  for (int ct = 0; ct < 4; ++ct) {
    int o = ob * 64 + ct * 16 + l16;
    const bf16x8* brow = (const bf16x8*)(wqkv + (size_t)o * 256);
    f32x4 c = {0.f, 0.f, 0.f, 0.f};
    for (int ks = 0; ks < 8; ++ks)
      c = __builtin_amdgcn_mfma_f32_16x16x32_bf16(a[ks], brow[ks * 4 + kgrp], c, 0, 0, 0);
    acc[ct] = c;
  }
  const float SCALE = 0.0625f * 1.44269504088896340736f;  // (1/sqrt(C)) * log2(e)
  for (int ct = 0; ct < 4; ++ct) {
    int o = ob * 64 + ct * 16 + l16;
    for (int r = 0; r < 4; ++r) {
      int n = nb * 64 + w * 16 + kgrp * 4 + r;
      float v = acc[ct][r];
      if (o < 256) qT[(size_t)n * 256 + o] = f2bf((v + qb[o]) * SCALE);
      else if (o < 512) kT[(size_t)n * 256 + (o - 256)] = f2bf(v + kb[o - 256]);
      else vT[(size_t)n * 256 + (o - 512)] = f2bf(v + vb[o - 512]);
    }
  }
}

// ---------------- K4: transpose vT [8192][256] -> v_cm [256][8192] ----------
__global__ __launch_bounds__(256) void k_transv(const ushort* __restrict__ vT,
                                                ushort* __restrict__ v_cm) {
  __shared__ ushort tile[64][66];
  int n0 = blockIdx.x * 64, c0 = blockIdx.y * 64;
  int t = threadIdx.x, colr = t & 63, rq = t >> 6;
  for (int rr = 0; rr < 16; ++rr) {
    int row = rr * 4 + rq;  // n-local
    tile[row][colr] = vT[(size_t)(n0 + row) * 256 + c0 + colr];
  }
  __syncthreads();
  for (int rr = 0; rr < 16; ++rr) {
    int rowW = rr * 4 + rq;  // c-local
    v_cm[(size_t)(c0 + rowW) * NSP + n0 + colr] = tile[colr][rowW];
  }
}

// ---------------- K5a: flash attention, 2-way key split ---------------------
// grid (128 qblocks, 2 splits) x 256 threads. Wave w handles 16 queries.
__global__ __launch_bounds__(256) void k_attn(const ushort* __restrict__ qT, const ushort* __restrict__ kT,
                                              const ushort* __restrict__ v_cm,
                                              float* __restrict__ Opart, float* __restrict__ mpart,
                                              float* __restrict__ lpart) {
  __shared__ __align__(16) ushort k_lds[64 * 256];   // [key][c], XOR-swizzled 16B granules
  __shared__ __align__(16) ushort v_lds[256 * 64];   // [c][key], XOR-swizzled
  __shared__ __align__(16) ushort p_lds[4][16][72];  // per-wave P, padded stride
  int qblk = blockIdx.x, split = blockIdx.y;
  int t = threadIdx.x, w = t >> 6, lane = t & 63;
  int l16 = lane & 15, kgrp = lane >> 4;
  int q0 = qblk * 64 + w * 16;

  bf16x8 qa[8];
  {
    const bf16x8* qrow = (const bf16x8*)(qT + (size_t)(q0 + l16) * 256);
    for (int ks = 0; ks < 8; ++ks) qa[ks] = qrow[ks * 4 + kgrp];
  }
  f32x4 o_acc[16] = {};
  float m_r[4] = {-INFINITY, -INFINITY, -INFINITY, -INFINITY};
  float l_r[4] = {0.f, 0.f, 0.f, 0.f};

  const char* kT_b = (const char*)kT;
  const char* v_b = (const char*)v_cm;

  for (int kb = 0; kb < 64; ++kb) {
    int kbase = split * 4096 + kb * 64;
    __syncthreads();  // all waves finished reading previous tiles
    // stage K tile: kT[kbase..kbase+64)[0..256) = 32KB, swizzled source
    for (int call = 0; call < 8; ++call) {
      int b = call * 4096 + w * 1024 + lane * 16;
      int row = b >> 9;
      int gs = ((b >> 4) & 31) ^ (row & 7);
      gload_lds16(kT_b + ((size_t)(kbase + row) << 9) + (gs << 4),
                  (char*)k_lds + call * 4096 + w * 1024);
    }
    // stage V tile: v_cm[0..256)[kbase..kbase+64) = 32KB, swizzled source
    for (int call = 0; call < 8; ++call) {
      int b = call * 4096 + w * 1024 + lane * 16;
      int c = b >> 7;
      int gs = ((b >> 4) & 7) ^ (c & 7);
      gload_lds16(v_b + ((size_t)c << 14) + ((size_t)kbase << 1) + (gs << 4),
                  (char*)v_lds + call * 4096 + w * 1024);
    }
    __syncthreads();  // drains vmcnt(0) then barrier
    // S tile: 16 queries x 64 keys
    f32x4 s[4];
    for (int ct = 0; ct < 4; ++ct) {
      int krow = ct * 16 + l16;
      f32x4 acc = {0.f, 0.f, 0.f, 0.f};
      for (int ks = 0; ks < 8; ++ks) {
        int g = ks * 4 + kgrp;
        bf16x8 bf = *(const bf16x8*)(&k_lds[(krow << 8) + ((g ^ (krow & 7)) << 3)]);
        acc = __builtin_amdgcn_mfma_f32_16x16x32_bf16(qa[ks], bf, acc, 0, 0, 0);
      }
      s[ct] = acc;
    }
    // online softmax (log2 domain; scale pre-folded into q)
    float alpha[4];
    for (int r = 0; r < 4; ++r) {
      float tm = fmaxf(fmaxf(s[0][r], s[1][r]), fmaxf(s[2][r], s[3][r]));
      for (int msk = 1; msk < 16; msk <<= 1) tm = fmaxf(tm, __shfl_xor(tm, msk));
      float mn = fmaxf(m_r[r], tm);
      alpha[r] = __builtin_amdgcn_exp2f(m_r[r] - mn);
      m_r[r] = mn;
      float rs = 0.f;
      for (int ct = 0; ct < 4; ++ct) {
        float p = __builtin_amdgcn_exp2f(s[ct][r] - mn);
        s[ct][r] = p;
        rs += p;
      }
      for (int msk = 1; msk < 16; msk <<= 1) rs += __shfl_xor(rs, msk);
      l_r[r] = alpha[r] * l_r[r] + rs;
    }
    // P -> per-wave LDS (bf16)
    for (int ct = 0; ct < 4; ++ct)
      for (int r = 0; r < 4; ++r)
        p_lds[w][kgrp * 4 + r][ct * 16 + l16] = f2bf(s[ct][r]);
    asm volatile("s_waitcnt lgkmcnt(0)" ::: "memory");
    __builtin_amdgcn_sched_barrier(0);
    // rescale O
    for (int ct = 0; ct < 16; ++ct)
      for (int r = 0; r < 4; ++r) o_acc[ct][r] *= alpha[r];
    // PV: O[16q][256c] += P[16q][64m] * V[64m][256c]
    for (int ks = 0; ks < 2; ++ks) {
      bf16x8 pa = *(const bf16x8*)(&p_lds[w][l16][ks * 32 + kgrp * 8]);
      for (int ct = 0; ct < 16; ++ct) {
        int crow = ct * 16 + l16;
        int g = ks * 4 + kgrp;
        bf16x8 vf = *(const bf16x8*)(&v_lds[(crow << 6) + ((g ^ (crow & 7)) << 3)]);
        o_acc[ct] = __builtin_amdgcn_mfma_f32_16x16x32_bf16(pa, vf, o_acc[ct], 0, 0, 0);
      }
    }
  }
  // write partials
  size_t obase = ((size_t)split * NSP + q0) * 256;
  for (int ct = 0; ct < 16; ++ct)
    for (int r = 0; r < 4; ++r)
      Opart[obase + (size_t)(kgrp * 4 + r) * 256 + ct * 16 + l16] = o_acc[ct][r];
  if (l16 == 0) {
    for (int r = 0; r < 4; ++r) {
      int q = q0 + kgrp * 4 + r;
      mpart[split * NSP + q] = m_r[r];
      lpart[split * NSP + q] = l_r[r];
    }
  }
}

// ---------------- K5b: combine split partials -> attT bf16 [8192][256] ------
__global__ __launch_bounds__(256) void k_combine(const float* __restrict__ Opart,
                                                 const float* __restrict__ mpart,
                                                 const float* __restrict__ lpart,
                                                 ushort* __restrict__ attT) {
  int q = blockIdx.x;
  int c = threadIdx.x;
  float m0 = mpart[q], m1 = mpart[NSP + q];
  float l0 = lpart[q], l1 = lpart[NSP + q];
  float M = fmaxf(m0, m1);
  float w0 = __builtin_amdgcn_exp2f(m0 - M), w1 = __builtin_amdgcn_exp2f(m1 - M);
  float L = w0 * l0 + w1 * l1;
  float v = (w0 * Opart[(size_t)q * 256 + c] + w1 * Opart[(size_t)(NSP + q) * 256 + c]) / L;
  attT[(size_t)q * 256 + c] = f2bf(v);
}

// ---------------- K6: out = xn + ow @ att + ob ------------------------------
__global__ __launch_bounds__(256) void k_final(const ushort* __restrict__ attT, const ushort* __restrict__ wo,
                                               const float* __restrict__ ob, const float* __restrict__ x,
                                               const float* __restrict__ gw, const float* __restrict__ gb,
                                               const float* __restrict__ stat, float* __restrict__ out) {
  int nb = blockIdx.x, obk = blockIdx.y;
  int w = threadIdx.x >> 6, lane = threadIdx.x & 63;
  int l16 = lane & 15, kgrp = lane >> 4;
  int orow = obk * 64 + w * 16 + l16;
  bf16x8 a[8];
  const bf16x8* arow = (const bf16x8*)(wo + (size_t)orow * 256);
  for (int ks = 0; ks < 8; ++ks) a[ks] = arow[ks * 4 + kgrp];
  float mean = stat[0], rinv = stat[1];
  f32x4 acc[4];
  for (int ct = 0; ct < 4; ++ct) {
    int n = nb * 64 + ct * 16 + l16;
    const bf16x8* brow = (const bf16x8*)(attT + (size_t)n * 256);
    f32x4 c = {0.f, 0.f, 0.f, 0.f};
    for (int ks = 0; ks < 8; ++ks)
      c = __builtin_amdgcn_mfma_f32_16x16x32_bf16(a[ks], brow[ks * 4 + kgrp], c, 0, 0, 0);
    acc[ct] = c;
  }
  for (int ct = 0; ct < 4; ++ct) {
    for (int r = 0; r < 4; ++r) {
      int o = obk * 64 + w * 16 + kgrp * 4 + r;
      int n = nb * 64 + ct * 16 + l16;
      float xv = x[(size_t)o * NSP + n];
      float xn = (xv - mean) * rinv * gw[o] + gb[o];
      out[(size_t)o * NSP + n] = xn + acc[ct][r] + ob[o];
    }
  }
}

extern "C" void kernel_launch(void* const* d_in, const int* in_sizes, int n_in,
                              void* d_out, int out_size, void* d_ws, size_t ws_size,
                              hipStream_t stream) {
  const float* x = (const float*)d_in[0];
  const float* gw = (const float*)d_in[1];
  const float* gb = (const float*)d_in[2];
  const float* qw = (const float*)d_in[3];
  const float* qbv = (const float*)d_in[4];
  const float* kw = (const float*)d_in[5];
  const float* kbv = (const float*)d_in[6];
  const float* vw = (const float*)d_in[7];
  const float* vbv = (const float*)d_in[8];
  const float* ow = (const float*)d_in[9];
  const float* obv = (const float*)d_in[10];
  float* out = (float*)d_out;
  char* ws = (char*)d_ws;
  const size_t KB = 1024, MB = 1048576;
  float* part = (float*)(ws);                  // 4 KB
  float* stat = (float*)(ws + 60 * KB);        // 2 floats
  ushort* wqkv = (ushort*)(ws + 64 * KB);      // 384 KB
  ushort* wo = (ushort*)(ws + 448 * KB);       // 128 KB
  ushort* xnT = (ushort*)(ws + 1 * MB);        // 4 MB (reused as attT after K3)
  ushort* qT = (ushort*)(ws + 5 * MB);         // 4 MB
  ushort* kT = (ushort*)(ws + 9 * MB);         // 4 MB
  ushort* vT = (ushort*)(ws + 13 * MB);        // 4 MB (dead after K4)
  ushort* v_cm = (ushort*)(ws + 17 * MB);      // 4 MB
  float* Opart = (float*)(ws + 21 * MB);       // 16 MB
  float* mpart = (float*)(ws + 37 * MB);       // 64 KB
  float* lpart = (float*)(ws + 37 * MB + 64 * KB);
  ushort* attT = xnT;  // alias: xnT dead after k_qkv

  k_stats1<<<512, 256, 0, stream>>>(x, part);
  k_stats2<<<1, 256, 0, stream>>>(part, stat);
  k_castw<<<1024, 256, 0, stream>>>(qw, kw, vw, ow, wqkv, wo);
  k_norm_t<<<dim3(128, 4), 256, 0, stream>>>(x, gw, gb, stat, xnT);
  k_qkv<<<dim3(128, 12), 256, 0, stream>>>(xnT, wqkv, qbv, kbv, vbv, qT, kT, vT);
  k_transv<<<dim3(128, 4), 256, 0, stream>>>(vT, v_cm);
  k_attn<<<dim3(128, 2), 256, 0, stream>>>(qT, kT, v_cm, Opart, mpart, lpart);
  k_combine<<<NSP, 256, 0, stream>>>(Opart, mpart, lpart, attT);
  k_final<<<dim3(128, 4), 256, 0, stream>>>(attT, wo, obv, x, gw, gb, stat, out);
}

// Round 2
// 244.932 us; speedup vs baseline: 1.2330x; 1.2330x over previous
//
#include <hip/hip_runtime.h>
#include <hip/hip_bf16.h>
#include <cstdint>

// Problem constants: B=1, C=256, F=8, H=32, W=32 -> N = 8192 spatial, 2M elements.
#define NSP 8192
#define CCH 256
#define KBLK 32
#define NSPLIT 4
#define KEYS_PER_SPLIT 2048
#define NTILES 64  // KEYS_PER_SPLIT / KBLK

typedef __attribute__((ext_vector_type(4))) float f32x4;
typedef __attribute__((ext_vector_type(8))) short bf16x8;

__device__ __forceinline__ ushort f2bf(float f) {
  union { float f; uint32_t u; } v; v.f = f;
  uint32_t r = (v.u + 0x7FFFu + ((v.u >> 16) & 1u)) >> 16;
  return (ushort)r;
}
__device__ __forceinline__ float bf2f(ushort u) {
  union { uint32_t u; float f; } v; v.u = ((uint32_t)u) << 16; return v.f;
}

// global -> LDS direct copy, 16B per lane. LDS dest must be wave-uniform base.
__device__ __forceinline__ void gload_lds16(const void* g, void* l) {
  auto gp = (const __attribute__((address_space(1))) uint32_t*)(uintptr_t)g;
  auto lp = (__attribute__((address_space(3))) uint32_t*)(uint32_t)(uintptr_t)l;
  __builtin_amdgcn_global_load_lds(gp, lp, 16, 0, 0);
}

// ---------------- K1a: per-block partial sum/sumsq over x (2M floats) -------
__global__ __launch_bounds__(256) void k_stats1(const float* __restrict__ x,
                                                float* __restrict__ part) {
  int t = threadIdx.x, b = blockIdx.x;
  float s = 0.f, ss = 0.f;
  const float4* x4 = (const float4*)x;
  for (int i = 0; i < 4; ++i) {
    float4 v = x4[(size_t)i * 131072 + b * 256 + t];
    s += v.x + v.y + v.z + v.w;
    ss += v.x * v.x + v.y * v.y + v.z * v.z + v.w * v.w;
  }
  for (int m = 1; m < 64; m <<= 1) { s += __shfl_xor(s, m); ss += __shfl_xor(ss, m); }
  __shared__ float ls[4], lss[4];
  int w = t >> 6, lane = t & 63;
  if (lane == 0) { ls[w] = s; lss[w] = ss; }
  __syncthreads();
  if (t == 0) {
    part[b * 2 + 0] = ls[0] + ls[1] + ls[2] + ls[3];
    part[b * 2 + 1] = lss[0] + lss[1] + lss[2] + lss[3];
  }
}

// ---------------- K1b: finalize mean / rsqrt(var+eps) ----------------------
__global__ __launch_bounds__(256) void k_stats2(const float* __restrict__ part,
                                                float* __restrict__ stat) {
  int t = threadIdx.x;
  float s = 0.f, ss = 0.f;
  for (int i = t; i < 512; i += 256) { s += part[i * 2]; ss += part[i * 2 + 1]; }
  for (int m = 1; m < 64; m <<= 1) { s += __shfl_xor(s, m); ss += __shfl_xor(ss, m); }
  __shared__ float ls[4], lss[4];
  int w = t >> 6, lane = t & 63;
  if (lane == 0) { ls[w] = s; lss[w] = ss; }
  __syncthreads();
  if (t == 0) {
    float sum = ls[0] + ls[1] + ls[2] + ls[3];
    float ssum = lss[0] + lss[1] + lss[2] + lss[3];
    float mean = sum * (1.f / 2097152.f);
    float var = ssum * (1.f / 2097152.f) - mean * mean;
    stat[0] = mean;
    stat[1] = rsqrtf(var + 1e-5f);
  }
}

// ---------------- K2a: cast weights to bf16 ---------------------------------
__global__ __launch_bounds__(256) void k_castw(const float* __restrict__ qw, const float* __restrict__ kw,
                                               const float* __restrict__ vw, const float* __restrict__ ow,
                                               ushort* __restrict__ wqkv, ushort* __restrict__ wo) {
  int idx = blockIdx.x * 256 + threadIdx.x;  // grid 1024 -> 262144
  if (idx < 65536) wqkv[idx] = f2bf(qw[idx]);
  else if (idx < 131072) wqkv[idx] = f2bf(kw[idx - 65536]);
  else if (idx < 196608) wqkv[idx] = f2bf(vw[idx - 131072]);
  else wo[idx - 196608] = f2bf(ow[idx - 196608]);
}

// ---------------- K2b: normalize + transpose -> xnT bf16 [8192][256] --------
__global__ __launch_bounds__(256) void k_norm_t(const float* __restrict__ x,
                                                const float* __restrict__ gw, const float* __restrict__ gb,
                                                const float* __restrict__ stat, ushort* __restrict__ xnT) {
  __shared__ float tile[64][66];
  int n0 = blockIdx.x * 64, c0 = blockIdx.y * 64;
  int t = threadIdx.x, colr = t & 63, rq = t >> 6;
  float mean = stat[0], rinv = stat[1];
  for (int rr = 0; rr < 16; ++rr) {
    int row = rr * 4 + rq;  // c-local
    int c = c0 + row;
    float v = x[(size_t)c * NSP + n0 + colr];
    tile[row][colr] = (v - mean) * rinv * gw[c] + gb[c];
  }
  __syncthreads();
  for (int rr = 0; rr < 16; ++rr) {
    int rowW = rr * 4 + rq;  // n-local
    xnT[(size_t)(n0 + rowW) * 256 + c0 + colr] = f2bf(tile[colr][rowW]);
  }
}

// ---------------- K3: QKV GEMM -> qT(scaled)/kT/vT [8192][256] bf16 ---------
__global__ __launch_bounds__(256) void k_qkv(const ushort* __restrict__ xnT, const ushort* __restrict__ wqkv,
                                             const float* __restrict__ qb, const float* __restrict__ kb,
                                             const float* __restrict__ vb,
                                             ushort* __restrict__ qT, ushort* __restrict__ kT,
                                             ushort* __restrict__ vT) {
  int nb = blockIdx.x, ob = blockIdx.y;
  int w = threadIdx.x >> 6, lane = threadIdx.x & 63;
  int l16 = lane & 15, kgrp = lane >> 4;
  int n_row = nb * 64 + w * 16 + l16;
  bf16x8 a[8];
  const bf16x8* arow = (const bf16x8*)(xnT + (size_t)n_row * 256);
  for (int ks = 0; ks < 8; ++ks) a[ks] = arow[ks * 4 + kgrp];
  f32x4 acc[4];
  for (int ct = 0; ct < 4; ++ct) {
    int o = ob * 64 + ct * 16 + l16;
    const bf16x8* brow = (const bf16x8*)(wqkv + (size_t)o * 256);
    f32x4 c = {0.f, 0.f, 0.f, 0.f};
    for (int ks = 0; ks < 8; ++ks)
      c = __builtin_amdgcn_mfma_f32_16x16x32_bf16(a[ks], brow[ks * 4 + kgrp], c, 0, 0, 0);
    acc[ct] = c;
  }
  const float SCALE = 0.0625f * 1.44269504088896340736f;  // (1/sqrt(C)) * log2(e)
  for (int ct = 0; ct < 4; ++ct) {
    int o = ob * 64 + ct * 16 + l16;
    for (int r = 0; r < 4; ++r) {
      int n = nb * 64 + w * 16 + kgrp * 4 + r;
      float v = acc[ct][r];
      if (o < 256) qT[(size_t)n * 256 + o] = f2bf((v + qb[o]) * SCALE);
      else if (o < 512) kT[(size_t)n * 256 + (o - 256)] = f2bf(v + kb[o - 256]);
      else vT[(size_t)n * 256 + (o - 512)] = f2bf(v + vb[o - 512]);
    }
  }
}

// ---------------- K4: transpose vT [8192][256] -> v_cm [256][8192] ----------
__global__ __launch_bounds__(256) void k_transv(const ushort* __restrict__ vT,
                                                ushort* __restrict__ v_cm) {
  __shared__ ushort tile[64][66];
  int n0 = blockIdx.x * 64, c0 = blockIdx.y * 64;
  int t = threadIdx.x, colr = t & 63, rq = t >> 6;
  for (int rr = 0; rr < 16; ++rr) {
    int row = rr * 4 + rq;  // n-local
    tile[row][colr] = vT[(size_t)(n0 + row) * 256 + c0 + colr];
  }
  __syncthreads();
  for (int rr = 0; rr < 16; ++rr) {
    int rowW = rr * 4 + rq;  // c-local
    v_cm[(size_t)(c0 + rowW) * NSP + n0 + colr] = tile[colr][rowW];
  }
}

// ---------------- K5a: flash attention, 4-way key split, dbuf + counted vmcnt
// grid (128 qblocks, 4 splits) x 256 threads. Wave w handles 16 queries.
// LDS 69KB/block -> 2 blocks/CU (8 waves) for cross-block latency hiding.
__global__ __launch_bounds__(256) void k_attn(const ushort* __restrict__ qT, const ushort* __restrict__ kT,
                                              const ushort* __restrict__ v_cm,
                                              ushort* __restrict__ Opart, float* __restrict__ mpart,
                                              float* __restrict__ lpart) {
  __shared__ __align__(16) ushort k_lds[2][KBLK * 256];   // 2 x 16KB, [key][c] swizzled
  __shared__ __align__(16) ushort v_lds[2][256 * KBLK];   // 2 x 16KB, [c][key] swizzled
  __shared__ __align__(16) ushort p_lds[4][16][40];       // per-wave P (5KB)
  int qblk = blockIdx.x, split = blockIdx.y;
  int t = threadIdx.x, w = t >> 6, lane = t & 63;
  int l16 = lane & 15, kgrp = lane >> 4;
  int q0 = qblk * 64 + w * 16;

  bf16x8 qa[8];
  {
    const bf16x8* qrow = (const bf16x8*)(qT + (size_t)(q0 + l16) * 256);
    for (int ks = 0; ks < 8; ++ks) qa[ks] = qrow[ks * 4 + kgrp];
  }
  f32x4 o_acc[16] = {};
  float m_r[4] = {-1e30f, -1e30f, -1e30f, -1e30f};
  float l_p[4] = {0.f, 0.f, 0.f, 0.f};

  const char* kT_b = (const char*)(kT + (size_t)split * KEYS_PER_SPLIT * 256);
  const char* v_b = (const char*)v_cm + (size_t)split * KEYS_PER_SPLIT * 2;

  // stage tile tt into buffer bsel: K 16KB + V 16KB, 4+4 gload_lds per thread
  auto STAGE = [&](int tt, int bsel) {
    const char* ksrc = kT_b + ((size_t)tt * KBLK) * 512;
    for (int cl = 0; cl < 4; ++cl) {
      int b = cl * 4096 + w * 1024 + lane * 16;
      int row = b >> 9;                                   // 0..31 key-local
      int gs = ((b >> 4) & 31) ^ (row & 7);               // XOR-swizzled source
      gload_lds16(ksrc + ((size_t)row << 9) + (gs << 4),
                  (char*)&k_lds[bsel][0] + cl * 4096 + w * 1024);
    }
    const char* vsrc = v_b + ((size_t)tt * KBLK) * 2;
    for (int cl = 0; cl < 4; ++cl) {
      int b = cl * 4096 + w * 1024 + lane * 16;
      int c = b >> 6;                                     // 0..255 channel
      int sw = (c & 3) ^ ((c >> 2) & 3);
      int gs = ((b >> 4) & 3) ^ sw;
      gload_lds16(vsrc + ((size_t)c << 14) + (gs << 4),
                  (char*)&v_lds[bsel][0] + cl * 4096 + w * 1024);
    }
  };

  STAGE(0, 0);  // prologue

  for (int tt = 0; tt < NTILES; ++tt) {
    int cur = tt & 1;
    if (tt + 1 < NTILES) {
      STAGE(tt + 1, cur ^ 1);
      asm volatile("s_waitcnt vmcnt(8)" ::: "memory");   // tile tt's 8 loads done
    } else {
      asm volatile("s_waitcnt vmcnt(0)" ::: "memory");
    }
    __builtin_amdgcn_s_barrier();  // all waves' tile-tt data visible

    // ---- QK^T: S[16q][32k] ----
    const ushort* kl = &k_lds[cur][0];
    __builtin_amdgcn_s_setprio(1);
    f32x4 s0 = {0.f, 0.f, 0.f, 0.f}, s1 = {0.f, 0.f, 0.f, 0.f};
    int krow0 = l16, krow1 = 16 + l16;
    for (int ks = 0; ks < 8; ++ks) {
      int g = ks * 4 + kgrp;
      bf16x8 b0 = *(const bf16x8*)(kl + (krow0 << 8) + ((g ^ (krow0 & 7)) << 3));
      s0 = __builtin_amdgcn_mfma_f32_16x16x32_bf16(qa[ks], b0, s0, 0, 0, 0);
      bf16x8 b1 = *(const bf16x8*)(kl + (krow1 << 8) + ((g ^ (krow1 & 7)) << 3));
      s1 = __builtin_amdgcn_mfma_f32_16x16x32_bf16(qa[ks], b1, s1, 0, 0, 0);
    }
    __builtin_amdgcn_s_setprio(0);

    // ---- online softmax, defer-max fast path (no shuffles, no rescale) ----
    float pm[4];
    for (int r = 0; r < 4; ++r) pm[r] = fmaxf(s0[r], s1[r]);
    bool ok = (pm[0] <= m_r[0] + 8.f) && (pm[1] <= m_r[1] + 8.f) &&
              (pm[2] <= m_r[2] + 8.f) && (pm[3] <= m_r[3] + 8.f);
    if (!__all(ok)) {
      for (int r = 0; r < 4; ++r) {
        float tm = pm[r];
        for (int msk = 1; msk < 16; msk <<= 1) tm = fmaxf(tm, __shfl_xor(tm, msk));
        float mn = fmaxf(m_r[r], tm);
        float alpha = __builtin_amdgcn_exp2f(m_r[r] - mn);
        m_r[r] = mn;
        l_p[r] *= alpha;
        for (int ct = 0; ct < 16; ++ct) o_acc[ct][r] *= alpha;
      }
    }
    for (int r = 0; r < 4; ++r) {
      float p0 = __builtin_amdgcn_exp2f(s0[r] - m_r[r]);
      float p1 = __builtin_amdgcn_exp2f(s1[r] - m_r[r]);
      l_p[r] += p0 + p1;
      p_lds[w][kgrp * 4 + r][l16] = f2bf(p0);
      p_lds[w][kgrp * 4 + r][16 + l16] = f2bf(p1);
    }
    asm volatile("s_waitcnt lgkmcnt(0)" ::: "memory");
    __builtin_amdgcn_sched_barrier(0);

    // ---- PV: O[16q][256c] += P[16q][32m] V[32m][256c] ----
    bf16x8 pa = *(const bf16x8*)(&p_lds[w][l16][kgrp * 8]);
    const ushort* vl = &v_lds[cur][0];
    __builtin_amdgcn_s_setprio(1);
    for (int ct = 0; ct < 16; ++ct) {
      int crow = ct * 16 + l16;
      int g = kgrp ^ ((crow & 3) ^ ((crow >> 2) & 3));
      bf16x8 vf = *(const bf16x8*)(vl + (crow << 5) + (g << 3));
      o_acc[ct] = __builtin_amdgcn_mfma_f32_16x16x32_bf16(pa, vf, o_acc[ct], 0, 0, 0);
    }
    __builtin_amdgcn_s_setprio(0);
    __builtin_amdgcn_s_barrier();  // all waves done reading buf[cur]
  }

  // final l reduction across the 16-lane subgroup
  for (int r = 0; r < 4; ++r)
    for (int msk = 1; msk < 16; msk <<= 1) l_p[r] += __shfl_xor(l_p[r], msk);

  // write partials (bf16 O)
  size_t obase = ((size_t)split * NSP + q0) * 256;
  for (int ct = 0; ct < 16; ++ct)
    for (int r = 0; r < 4; ++r)
      Opart[obase + (size_t)(kgrp * 4 + r) * 256 + ct * 16 + l16] = f2bf(o_acc[ct][r]);
  if (l16 == 0) {
    for (int r = 0; r < 4; ++r) {
      int q = q0 + kgrp * 4 + r;
      mpart[split * NSP + q] = m_r[r];
      lpart[split * NSP + q] = l_p[r];
    }
  }
}

// ---------------- K5b: combine split partials -> attT bf16 [8192][256] ------
__global__ __launch_bounds__(256) void k_combine(const ushort* __restrict__ Opart,
                                                 const float* __restrict__ mpart,
                                                 const float* __restrict__ lpart,
                                                 ushort* __restrict__ attT) {
  int q = blockIdx.x;
  int c = threadIdx.x;
  float m[NSPLIT], l[NSPLIT];
  float M = -1e30f;
  for (int s = 0; s < NSPLIT; ++s) {
    m[s] = mpart[s * NSP + q];
    l[s] = lpart[s * NSP + q];
    M = fmaxf(M, m[s]);
  }
  float L = 0.f, acc = 0.f;
  for (int s = 0; s < NSPLIT; ++s) {
    float ws = __builtin_amdgcn_exp2f(m[s] - M);
    L += ws * l[s];
    acc += ws * bf2f(Opart[((size_t)s * NSP + q) * 256 + c]);
  }
  attT[(size_t)q * 256 + c] = f2bf(acc / L);
}

// ---------------- K6: out = xn + ow @ att + ob ------------------------------
__global__ __launch_bounds__(256) void k_final(const ushort* __restrict__ attT, const ushort* __restrict__ wo,
                                               const float* __restrict__ ob, const float* __restrict__ x,
                                               const float* __restrict__ gw, const float* __restrict__ gb,
                                               const float* __restrict__ stat, float* __restrict__ out) {
  int nb = blockIdx.x, obk = blockIdx.y;
  int w = threadIdx.x >> 6, lane = threadIdx.x & 63;
  int l16 = lane & 15, kgrp = lane >> 4;
  int orow = obk * 64 + w * 16 + l16;
  bf16x8 a[8];
  const bf16x8* arow = (const bf16x8*)(wo + (size_t)orow * 256);
  for (int ks = 0; ks < 8; ++ks) a[ks] = arow[ks * 4 + kgrp];
  float mean = stat[0], rinv = stat[1];
  f32x4 acc[4];
  for (int ct = 0; ct < 4; ++ct) {
    int n = nb * 64 + ct * 16 + l16;
    const bf16x8* brow = (const bf16x8*)(attT + (size_t)n * 256);
    f32x4 c = {0.f, 0.f, 0.f, 0.f};
    for (int ks = 0; ks < 8; ++ks)
      c = __builtin_amdgcn_mfma_f32_16x16x32_bf16(a[ks], brow[ks * 4 + kgrp], c, 0, 0, 0);
    acc[ct] = c;
  }
  for (int ct = 0; ct < 4; ++ct) {
    for (int r = 0; r < 4; ++r) {
      int o = obk * 64 + w * 16 + kgrp * 4 + r;
      int n = nb * 64 + ct * 16 + l16;
      float xv = x[(size_t)o * NSP + n];
      float xn = (xv - mean) * rinv * gw[o] + gb[o];
      out[(size_t)o * NSP + n] = xn + acc[ct][r] + ob[o];
    }
  }
}

extern "C" void kernel_launch(void* const* d_in, const int* in_sizes, int n_in,
                              void* d_out, int out_size, void* d_ws, size_t ws_size,
                              hipStream_t stream) {
  const float* x = (const float*)d_in[0];
  const float* gw = (const float*)d_in[1];
  const float* gb = (const float*)d_in[2];
  const float* qw = (const float*)d_in[3];
  const float* qbv = (const float*)d_in[4];
  const float* kw = (const float*)d_in[5];
  const float* kbv = (const float*)d_in[6];
  const float* vw = (const float*)d_in[7];
  const float* vbv = (const float*)d_in[8];
  const float* ow = (const float*)d_in[9];
  const float* obv = (const float*)d_in[10];
  float* out = (float*)d_out;
  char* ws = (char*)d_ws;
  const size_t KB = 1024, MB = 1048576;
  float* part = (float*)(ws);                  // 4 KB
  float* stat = (float*)(ws + 60 * KB);        // 2 floats
  ushort* wqkv = (ushort*)(ws + 64 * KB);      // 384 KB
  ushort* wo = (ushort*)(ws + 448 * KB);       // 128 KB
  ushort* xnT = (ushort*)(ws + 1 * MB);        // 4 MB (reused as attT after K3)
  ushort* qT = (ushort*)(ws + 5 * MB);         // 4 MB
  ushort* kT = (ushort*)(ws + 9 * MB);         // 4 MB
  ushort* vT = (ushort*)(ws + 13 * MB);        // 4 MB (dead after K4)
  ushort* v_cm = (ushort*)(ws + 17 * MB);      // 4 MB
  ushort* Opart = (ushort*)(ws + 21 * MB);     // 16 MB (4 splits, bf16)
  float* mpart = (float*)(ws + 37 * MB);       // 128 KB
  float* lpart = (float*)(ws + 37 * MB + 128 * KB);  // 128 KB
  ushort* attT = xnT;  // alias: xnT dead after k_qkv

  k_stats1<<<512, 256, 0, stream>>>(x, part);
  k_stats2<<<1, 256, 0, stream>>>(part, stat);
  k_castw<<<1024, 256, 0, stream>>>(qw, kw, vw, ow, wqkv, wo);
  k_norm_t<<<dim3(128, 4), 256, 0, stream>>>(x, gw, gb, stat, xnT);
  k_qkv<<<dim3(128, 12), 256, 0, stream>>>(xnT, wqkv, qbv, kbv, vbv, qT, kT, vT);
  k_transv<<<dim3(128, 4), 256, 0, stream>>>(vT, v_cm);
  k_attn<<<dim3(128, NSPLIT), 256, 0, stream>>>(qT, kT, v_cm, Opart, mpart, lpart);
  k_combine<<<NSP, 256, 0, stream>>>(Opart, mpart, lpart, attT);
  k_final<<<dim3(128, 4), 256, 0, stream>>>(attT, wo, obv, x, gw, gb, stat, out);
}

// Round 3
// 176.894 us; speedup vs baseline: 1.7073x; 1.3846x over previous
//
#include <hip/hip_runtime.h>
#include <hip/hip_bf16.h>
#include <cstdint>

// Problem constants: B=1, C=256, F=8, H=32, W=32 -> N = 8192 spatial.
#define NSP 8192
#define CCH 256
#define KBLK 64
#define NSPLIT 4
#define KEYS_PER_SPLIT 2048
#define NTILES 32  // KEYS_PER_SPLIT / KBLK

typedef __attribute__((ext_vector_type(4))) float f32x4;
typedef __attribute__((ext_vector_type(16))) float f32x16;
typedef __attribute__((ext_vector_type(8))) short bf16x8;
typedef __attribute__((ext_vector_type(2))) unsigned int u32x2;

__device__ __forceinline__ ushort f2bf(float f) {
  union { float f; uint32_t u; } v; v.f = f;
  uint32_t r = (v.u + 0x7FFFu + ((v.u >> 16) & 1u)) >> 16;
  return (ushort)r;
}
__device__ __forceinline__ float bf2f(ushort u) {
  union { uint32_t u; float f; } v; v.u = ((uint32_t)u) << 16; return v.f;
}
// pack two f32 -> one u32 of 2 bf16 (lo = first arg); compiler emits v_cvt_pk_bf16_f32
__device__ __forceinline__ uint32_t pk2bf(float lo, float hi) {
  __hip_bfloat162 h = __float22bfloat162_rn({lo, hi});
  union { __hip_bfloat162 h; uint32_t u; } c; c.h = h; return c.u;
}

// global -> LDS direct copy, 16B per lane. LDS dest must be wave-uniform base.
__device__ __forceinline__ void gload_lds16(const void* g, void* l) {
  auto gp = (const __attribute__((address_space(1))) uint32_t*)(uintptr_t)g;
  auto lp = (__attribute__((address_space(3))) uint32_t*)(uint32_t)(uintptr_t)l;
  __builtin_amdgcn_global_load_lds(gp, lp, 16, 0, 0);
}

// exchange: swaps hi 32 lanes of a with lo 32 lanes of b; returns {a_new, b_new}
__device__ __forceinline__ void perm32swap(uint32_t& a, uint32_t& b) {
#if __has_builtin(__builtin_amdgcn_permlane32_swap)
  u32x2 r = __builtin_amdgcn_permlane32_swap(a, b, false, false);
  a = r[0]; b = r[1];
#else
  uint32_t sa = __shfl_xor((int)a, 32), sb = __shfl_xor((int)b, 32);
  bool lo = (threadIdx.x & 63) < 32;
  uint32_t na = lo ? a : sb;
  uint32_t nb = lo ? sa : b;
  a = na; b = nb;
#endif
}

// ---------------- K1a: per-block partial sum/sumsq over x (2M floats) -------
__global__ __launch_bounds__(256) void k_stats1(const float* __restrict__ x,
                                                float* __restrict__ part) {
  int t = threadIdx.x, b = blockIdx.x;
  float s = 0.f, ss = 0.f;
  const float4* x4 = (const float4*)x;
  for (int i = 0; i < 4; ++i) {
    float4 v = x4[(size_t)i * 131072 + b * 256 + t];
    s += v.x + v.y + v.z + v.w;
    ss += v.x * v.x + v.y * v.y + v.z * v.z + v.w * v.w;
  }
  for (int m = 1; m < 64; m <<= 1) { s += __shfl_xor(s, m); ss += __shfl_xor(ss, m); }
  __shared__ float ls[4], lss[4];
  int w = t >> 6, lane = t & 63;
  if (lane == 0) { ls[w] = s; lss[w] = ss; }
  __syncthreads();
  if (t == 0) {
    part[b * 2 + 0] = ls[0] + ls[1] + ls[2] + ls[3];
    part[b * 2 + 1] = lss[0] + lss[1] + lss[2] + lss[3];
  }
}

// ---------------- K1b: finalize mean / rsqrt(var+eps) ----------------------
__global__ __launch_bounds__(256) void k_stats2(const float* __restrict__ part,
                                                float* __restrict__ stat) {
  int t = threadIdx.x;
  float s = 0.f, ss = 0.f;
  for (int i = t; i < 512; i += 256) { s += part[i * 2]; ss += part[i * 2 + 1]; }
  for (int m = 1; m < 64; m <<= 1) { s += __shfl_xor(s, m); ss += __shfl_xor(ss, m); }
  __shared__ float ls[4], lss[4];
  int w = t >> 6, lane = t & 63;
  if (lane == 0) { ls[w] = s; lss[w] = ss; }
  __syncthreads();
  if (t == 0) {
    float sum = ls[0] + ls[1] + ls[2] + ls[3];
    float ssum = lss[0] + lss[1] + lss[2] + lss[3];
    float mean = sum * (1.f / 2097152.f);
    float var = ssum * (1.f / 2097152.f) - mean * mean;
    stat[0] = mean;
    stat[1] = rsqrtf(var + 1e-5f);
  }
}

// ---------------- K2a: cast weights to bf16 ---------------------------------
__global__ __launch_bounds__(256) void k_castw(const float* __restrict__ qw, const float* __restrict__ kw,
                                               const float* __restrict__ vw, const float* __restrict__ ow,
                                               ushort* __restrict__ wqkv, ushort* __restrict__ wo) {
  int idx = blockIdx.x * 256 + threadIdx.x;  // grid 1024 -> 262144
  if (idx < 65536) wqkv[idx] = f2bf(qw[idx]);
  else if (idx < 131072) wqkv[idx] = f2bf(kw[idx - 65536]);
  else if (idx < 196608) wqkv[idx] = f2bf(vw[idx - 131072]);
  else wo[idx - 196608] = f2bf(ow[idx - 196608]);
}

// ---------------- K2b: normalize + transpose -> xnT bf16 [8192][256] --------
__global__ __launch_bounds__(256) void k_norm_t(const float* __restrict__ x,
                                                const float* __restrict__ gw, const float* __restrict__ gb,
                                                const float* __restrict__ stat, ushort* __restrict__ xnT) {
  __shared__ float tile[64][66];
  int n0 = blockIdx.x * 64, c0 = blockIdx.y * 64;
  int t = threadIdx.x, colr = t & 63, rq = t >> 6;
  float mean = stat[0], rinv = stat[1];
  for (int rr = 0; rr < 16; ++rr) {
    int row = rr * 4 + rq;  // c-local
    int c = c0 + row;
    float v = x[(size_t)c * NSP + n0 + colr];
    tile[row][colr] = (v - mean) * rinv * gw[c] + gb[c];
  }
  __syncthreads();
  for (int rr = 0; rr < 16; ++rr) {
    int rowW = rr * 4 + rq;  // n-local
    xnT[(size_t)(n0 + rowW) * 256 + c0 + colr] = f2bf(tile[colr][rowW]);
  }
}

// ---------------- K3: QKV GEMM -> qT(scaled)/kT/vT [8192][256] bf16 ---------
__global__ __launch_bounds__(256) void k_qkv(const ushort* __restrict__ xnT, const ushort* __restrict__ wqkv,
                                             const float* __restrict__ qb, const float* __restrict__ kb,
                                             const float* __restrict__ vb,
                                             ushort* __restrict__ qT, ushort* __restrict__ kT,
                                             ushort* __restrict__ vT) {
  int nb = blockIdx.x, ob = blockIdx.y;
  int w = threadIdx.x >> 6, lane = threadIdx.x & 63;
  int l16 = lane & 15, kgrp = lane >> 4;
  int n_row = nb * 64 + w * 16 + l16;
  bf16x8 a[8];
  const bf16x8* arow = (const bf16x8*)(xnT + (size_t)n_row * 256);
  for (int ks = 0; ks < 8; ++ks) a[ks] = arow[ks * 4 + kgrp];
  f32x4 acc[4];
  for (int ct = 0; ct < 4; ++ct) {
    int o = ob * 64 + ct * 16 + l16;
    const bf16x8* brow = (const bf16x8*)(wqkv + (size_t)o * 256);
    f32x4 c = {0.f, 0.f, 0.f, 0.f};
    for (int ks = 0; ks < 8; ++ks)
      c = __builtin_amdgcn_mfma_f32_16x16x32_bf16(a[ks], brow[ks * 4 + kgrp], c, 0, 0, 0);
    acc[ct] = c;
  }
  const float SCALE = 0.0625f * 1.44269504088896340736f;  // (1/sqrt(C)) * log2(e)
  for (int ct = 0; ct < 4; ++ct) {
    int o = ob * 64 + ct * 16 + l16;
    for (int r = 0; r < 4; ++r) {
      int n = nb * 64 + w * 16 + kgrp * 4 + r;
      float v = acc[ct][r];
      if (o < 256) qT[(size_t)n * 256 + o] = f2bf((v + qb[o]) * SCALE);
      else if (o < 512) kT[(size_t)n * 256 + (o - 256)] = f2bf(v + kb[o - 256]);
      else vT[(size_t)n * 256 + (o - 512)] = f2bf(v + vb[o - 512]);
    }
  }
}

// ---------------- K4: transpose vT [8192][256] -> v_cm [256][8192] ----------
__global__ __launch_bounds__(256) void k_transv(const ushort* __restrict__ vT,
                                                ushort* __restrict__ v_cm) {
  __shared__ ushort tile[64][66];
  int n0 = blockIdx.x * 64, c0 = blockIdx.y * 64;
  int t = threadIdx.x, colr = t & 63, rq = t >> 6;
  for (int rr = 0; rr < 16; ++rr) {
    int row = rr * 4 + rq;  // n-local
    tile[row][colr] = vT[(size_t)(n0 + row) * 256 + c0 + colr];
  }
  __syncthreads();
  for (int rr = 0; rr < 16; ++rr) {
    int rowW = rr * 4 + rq;  // c-local
    v_cm[(size_t)(c0 + rowW) * NSP + n0 + colr] = tile[colr][rowW];
  }
}

// ---------------- K5a: flash attention, 32x32 MFMA, in-register softmax -----
// grid (64 qblocks, 4 splits) x 256 threads. Wave w owns 32 queries.
// 1 block/CU, 1 wave/SIMD -> VGPR budget 512. LDS = 128KB (K dbuf 64K + V dbuf 64K).
// S = mfma(K, Q): S[key][q], col=lane&31=q, rows=keys per 32x32 C-layout.
// PV = mfma(V^T, P): O[c][q], A = V^T from LDS, B = P built in-register.
__global__ __launch_bounds__(256, 1) void k_attn(const ushort* __restrict__ qT, const ushort* __restrict__ kT,
                                                 const ushort* __restrict__ v_cm,
                                                 ushort* __restrict__ Opart, float* __restrict__ mpart,
                                                 float* __restrict__ lpart) {
  __shared__ __align__(16) ushort SMEM[65536];  // 128 KB
  ushort* k_lds = SMEM;           // 2 x 16384 ushorts ([64 key][256 c], 16B-slot XOR swizzled)
  ushort* v_lds = SMEM + 32768;   // 2 x 16384 ushorts ([256 c][64 m], 16B-slot XOR swizzled)

  int qblk = blockIdx.x, split = blockIdx.y;
  int t = threadIdx.x, w = t >> 6, lane = t & 63;
  int l31 = lane & 31, lhi = lane >> 5, l7 = lane & 7;
  int q0w = qblk * 128 + w * 32;

  // Q as B-operand fragments: lane holds q=l31, channels cs*16 + lhi*8 + j
  bf16x8 qf[16];
  {
    const char* qbase = (const char*)qT + (size_t)(q0w + l31) * 512;
#pragma unroll
    for (int cs = 0; cs < 16; ++cs)
      qf[cs] = *(const bf16x8*)(qbase + cs * 32 + lhi * 16);
  }

  f32x16 acc[8] = {};                 // O[c][q]: 8 blocks of 32 channels
  float m_r = -1e30f, l_p = 0.f;      // per-lane (query q = l31)

  const char* kT_b = (const char*)kT + (size_t)split * KEYS_PER_SPLIT * 512;
  const char* v_b = (const char*)v_cm + (size_t)split * KEYS_PER_SPLIT * 2;

  // stage tile tt (keys tt*64..+64) into buffer bsel. 16 gload_lds per thread-wave.
  auto STAGE = [&](int tt, int bsel) {
    // K: [64 key][512B], LDS[key][slot] = G[key][slot ^ (key&7)]
    const char* ksrc = kT_b + (size_t)tt * 64 * 512;
    char* kdst = (char*)(k_lds + bsel * 16384) + w * 8192;
#pragma unroll
    for (int i = 0; i < 8; ++i) {
      int keyloc = w * 16 + i * 2 + lhi;
      int srcoff = keyloc * 512 + ((l31 ^ (keyloc & 7)) << 4);
      gload_lds16(ksrc + srcoff, kdst + i * 1024);
    }
    // V: [256 c][128B], LDS[c][slot] = G[c][slot ^ (c&7)]
    const char* vsrc = v_b + (size_t)tt * 128;
    char* vdst = (char*)(v_lds + bsel * 16384) + w * 8192;
#pragma unroll
    for (int i = 0; i < 8; ++i) {
      int crow = w * 64 + i * 8 + (lane >> 3);
      int srcoff = crow * 16384 + (((lane & 7) ^ (crow & 7)) << 4);
      gload_lds16(vsrc + srcoff, vdst + i * 1024);
    }
  };

  STAGE(0, 0);  // prologue

#pragma unroll 1
  for (int tt = 0; tt < NTILES; ++tt) {
    int cur = tt & 1;
    if (tt + 1 < NTILES) {
      STAGE(tt + 1, cur ^ 1);
      asm volatile("s_waitcnt vmcnt(16)" ::: "memory");  // tile tt's 16 loads done
    } else {
      asm volatile("s_waitcnt vmcnt(0)" ::: "memory");
    }
    __builtin_amdgcn_s_barrier();

    // ---- QK^T: S[64 key][32 q] as two 32x32 tiles ----
    const ushort* kl = k_lds + cur * 16384;
    f32x16 S0 = {}, S1 = {};
    __builtin_amdgcn_s_setprio(1);
#pragma unroll
    for (int cs = 0; cs < 16; ++cs) {
      int slot = (cs * 2 + lhi) ^ l7;
      bf16x8 a0 = *(const bf16x8*)(kl + l31 * 256 + slot * 8);
      S0 = __builtin_amdgcn_mfma_f32_32x32x16_bf16(a0, qf[cs], S0, 0, 0, 0);
      bf16x8 a1 = *(const bf16x8*)(kl + (32 + l31) * 256 + slot * 8);
      S1 = __builtin_amdgcn_mfma_f32_32x32x16_bf16(a1, qf[cs], S1, 0, 0, 0);
    }
    __builtin_amdgcn_s_setprio(0);

    // ---- online softmax, in-register (lane owns query q=l31's 32 keys; partner l^32 other 32)
    float pm = S0[0];
#pragma unroll
    for (int r = 1; r < 16; ++r) pm = fmaxf(pm, S0[r]);
#pragma unroll
    for (int r = 0; r < 16; ++r) pm = fmaxf(pm, S1[r]);
    float pmB = fmaxf(pm, __shfl_xor(pm, 32));
    if (!__all(pmB <= m_r + 8.f)) {   // defer-max slow path (rare)
      float mn = fmaxf(m_r, pmB);
      float alpha = __builtin_amdgcn_exp2f(m_r - mn);
      m_r = mn;
      l_p *= alpha;
#pragma unroll
      for (int cb = 0; cb < 8; ++cb)
#pragma unroll
        for (int r = 0; r < 16; ++r) acc[cb][r] *= alpha;
    }
    float t0 = 0.f, t1 = 0.f, t2 = 0.f, t3 = 0.f;
#pragma unroll
    for (int r = 0; r < 16; ++r) {
      S0[r] = __builtin_amdgcn_exp2f(S0[r] - m_r);
      S1[r] = __builtin_amdgcn_exp2f(S1[r] - m_r);
      if (r < 4) { t0 += S0[r] + S1[r]; }
      else if (r < 8) { t1 += S0[r] + S1[r]; }
      else if (r < 12) { t2 += S0[r] + S1[r]; }
      else { t3 += S0[r] + S1[r]; }
    }
    l_p += (t0 + t1) + (t2 + t3);

    // ---- P -> bf16 B-fragments via cvt_pk + permlane32_swap ----
    // h-th fragment covers keys h*16..h*16+15; lane needs m = h*16 + lhi*8 + j.
    bf16x8 pf[4];
    {
      union { uint32_t w[4]; bf16x8 v; } u;
#pragma unroll
      for (int h = 0; h < 4; ++h) {
        const f32x16& S = (h < 2) ? S0 : S1;
        int b = (h & 1) * 8;
        uint32_t x = pk2bf(S[b + 0], S[b + 1]), y = pk2bf(S[b + 4], S[b + 5]);
        perm32swap(x, y);
        uint32_t x2 = pk2bf(S[b + 2], S[b + 3]), y2 = pk2bf(S[b + 6], S[b + 7]);
        perm32swap(x2, y2);
        u.w[0] = x; u.w[1] = x2; u.w[2] = y; u.w[3] = y2;
        pf[h] = u.v;
      }
    }

    // ---- PV: O[c][q] += V^T[c][m] P[m][q] ----
    const ushort* vl = v_lds + cur * 16384;
    __builtin_amdgcn_s_setprio(1);
#pragma unroll
    for (int cb = 0; cb < 8; ++cb) {
#pragma unroll
      for (int h = 0; h < 4; ++h) {
        int slot = (h * 2 + lhi) ^ l7;
        bf16x8 a = *(const bf16x8*)(vl + (cb * 32 + l31) * 64 + slot * 8);
        acc[cb] = __builtin_amdgcn_mfma_f32_32x32x16_bf16(a, pf[h], acc[cb], 0, 0, 0);
      }
    }
    __builtin_amdgcn_s_setprio(0);
    asm volatile("s_waitcnt lgkmcnt(0)" ::: "memory");
    __builtin_amdgcn_s_barrier();
  }

  // ---- epilogue: l reduce, O -> LDS transpose -> coalesced bf16 store ----
  float l_tot = l_p + __shfl_xor(l_p, 32);

  // per-wave scratch region: 32 q-rows x 528B (256 c x 2B + 16B pad)
  char* eb = (char*)SMEM + w * 17408;
#pragma unroll
  for (int cb = 0; cb < 8; ++cb) {
#pragma unroll
    for (int g = 0; g < 4; ++g) {
      int c0 = cb * 32 + g * 8 + 4 * lhi;
      uint32_t w0 = pk2bf(acc[cb][g * 4 + 0], acc[cb][g * 4 + 1]);
      uint32_t w1 = pk2bf(acc[cb][g * 4 + 2], acc[cb][g * 4 + 3]);
      *(uint32_t*)(eb + l31 * 528 + c0 * 2) = w0;
      *(uint32_t*)(eb + l31 * 528 + c0 * 2 + 4) = w1;
    }
  }
  size_t gq0 = (size_t)split * NSP + q0w;
#pragma unroll
  for (int i = 0; i < 16; ++i) {
    int flat = i * 1024 + lane * 16;
    int qr = flat >> 9;
    int off = flat & 511;
    uint4 val = *(const uint4*)(eb + qr * 528 + off);
    *(uint4*)((char*)Opart + (gq0 + qr) * 512 + off) = val;
  }
  if (lane < 32) {
    int q = q0w + lane;
    mpart[split * NSP + q] = m_r;
    lpart[split * NSP + q] = l_tot;
  }
}

// ---------------- K5b: combine split partials -> attT bf16 [8192][256] ------
__global__ __launch_bounds__(256) void k_combine(const ushort* __restrict__ Opart,
                                                 const float* __restrict__ mpart,
                                                 const float* __restrict__ lpart,
                                                 ushort* __restrict__ attT) {
  int q = blockIdx.x;
  int c = threadIdx.x;
  float m[NSPLIT], l[NSPLIT];
  float M = -1e30f;
  for (int s = 0; s < NSPLIT; ++s) {
    m[s] = mpart[s * NSP + q];
    l[s] = lpart[s * NSP + q];
    M = fmaxf(M, m[s]);
  }
  float L = 0.f, acc = 0.f;
  for (int s = 0; s < NSPLIT; ++s) {
    float ws = __builtin_amdgcn_exp2f(m[s] - M);
    L += ws * l[s];
    acc += ws * bf2f(Opart[((size_t)s * NSP + q) * 256 + c]);
  }
  attT[(size_t)q * 256 + c] = f2bf(acc / L);
}

// ---------------- K6: out = xn + ow @ att + ob ------------------------------
__global__ __launch_bounds__(256) void k_final(const ushort* __restrict__ attT, const ushort* __restrict__ wo,
                                               const float* __restrict__ ob, const float* __restrict__ x,
                                               const float* __restrict__ gw, const float* __restrict__ gb,
                                               const float* __restrict__ stat, float* __restrict__ out) {
  int nb = blockIdx.x, obk = blockIdx.y;
  int w = threadIdx.x >> 6, lane = threadIdx.x & 63;
  int l16 = lane & 15, kgrp = lane >> 4;
  int orow = obk * 64 + w * 16 + l16;
  bf16x8 a[8];
  const bf16x8* arow = (const bf16x8*)(wo + (size_t)orow * 256);
  for (int ks = 0; ks < 8; ++ks) a[ks] = arow[ks * 4 + kgrp];
  float mean = stat[0], rinv = stat[1];
  f32x4 acc[4];
  for (int ct = 0; ct < 4; ++ct) {
    int n = nb * 64 + ct * 16 + l16;
    const bf16x8* brow = (const bf16x8*)(attT + (size_t)n * 256);
    f32x4 c = {0.f, 0.f, 0.f, 0.f};
    for (int ks = 0; ks < 8; ++ks)
      c = __builtin_amdgcn_mfma_f32_16x16x32_bf16(a[ks], brow[ks * 4 + kgrp], c, 0, 0, 0);
    acc[ct] = c;
  }
  for (int ct = 0; ct < 4; ++ct) {
    for (int r = 0; r < 4; ++r) {
      int o = obk * 64 + w * 16 + kgrp * 4 + r;
      int n = nb * 64 + ct * 16 + l16;
      float xv = x[(size_t)o * NSP + n];
      float xn = (xv - mean) * rinv * gw[o] + gb[o];
      out[(size_t)o * NSP + n] = xn + acc[ct][r] + ob[o];
    }
  }
}

extern "C" void kernel_launch(void* const* d_in, const int* in_sizes, int n_in,
                              void* d_out, int out_size, void* d_ws, size_t ws_size,
                              hipStream_t stream) {
  const float* x = (const float*)d_in[0];
  const float* gw = (const float*)d_in[1];
  const float* gb = (const float*)d_in[2];
  const float* qw = (const float*)d_in[3];
  const float* qbv = (const float*)d_in[4];
  const float* kw = (const float*)d_in[5];
  const float* kbv = (const float*)d_in[6];
  const float* vw = (const float*)d_in[7];
  const float* vbv = (const float*)d_in[8];
  const float* ow = (const float*)d_in[9];
  const float* obv = (const float*)d_in[10];
  float* out = (float*)d_out;
  char* ws = (char*)d_ws;
  const size_t KB = 1024, MB = 1048576;
  float* part = (float*)(ws);                  // 4 KB
  float* stat = (float*)(ws + 60 * KB);        // 2 floats
  ushort* wqkv = (ushort*)(ws + 64 * KB);      // 384 KB
  ushort* wo = (ushort*)(ws + 448 * KB);       // 128 KB
  ushort* xnT = (ushort*)(ws + 1 * MB);        // 4 MB (reused as attT after K3)
  ushort* qT = (ushort*)(ws + 5 * MB);         // 4 MB
  ushort* kT = (ushort*)(ws + 9 * MB);         // 4 MB
  ushort* vT = (ushort*)(ws + 13 * MB);        // 4 MB (dead after K4)
  ushort* v_cm = (ushort*)(ws + 17 * MB);      // 4 MB
  ushort* Opart = (ushort*)(ws + 21 * MB);     // 16 MB (4 splits, bf16)
  float* mpart = (float*)(ws + 37 * MB);       // 128 KB
  float* lpart = (float*)(ws + 37 * MB + 128 * KB);  // 128 KB
  ushort* attT = xnT;  // alias: xnT dead after k_qkv

  k_stats1<<<512, 256, 0, stream>>>(x, part);
  k_stats2<<<1, 256, 0, stream>>>(part, stat);
  k_castw<<<1024, 256, 0, stream>>>(qw, kw, vw, ow, wqkv, wo);
  k_norm_t<<<dim3(128, 4), 256, 0, stream>>>(x, gw, gb, stat, xnT);
  k_qkv<<<dim3(128, 12), 256, 0, stream>>>(xnT, wqkv, qbv, kbv, vbv, qT, kT, vT);
  k_transv<<<dim3(128, 4), 256, 0, stream>>>(vT, v_cm);
  k_attn<<<dim3(64, NSPLIT), 256, 0, stream>>>(qT, kT, v_cm, Opart, mpart, lpart);
  k_combine<<<NSP, 256, 0, stream>>>(Opart, mpart, lpart, attT);
  k_final<<<dim3(128, 4), 256, 0, stream>>>(attT, wo, obv, x, gw, gb, stat, out);
}

// Round 4
// 171.227 us; speedup vs baseline: 1.7638x; 1.0331x over previous
//
#include <hip/hip_runtime.h>
#include <hip/hip_bf16.h>
#include <cstdint>

// Problem constants: B=1, C=256, F=8, H=32, W=32 -> N = 8192 spatial.
#define NSP 8192
#define CCH 256
#define KBLK 32
#define NSPLIT 8
#define KEYS_PER_SPLIT 1024
#define NTILES 32  // KEYS_PER_SPLIT / KBLK

typedef __attribute__((ext_vector_type(4))) float f32x4;
typedef __attribute__((ext_vector_type(16))) float f32x16;
typedef __attribute__((ext_vector_type(8))) short bf16x8;
typedef __attribute__((ext_vector_type(2))) unsigned int u32x2;

__device__ __forceinline__ ushort f2bf(float f) {
  union { float f; uint32_t u; } v; v.f = f;
  uint32_t r = (v.u + 0x7FFFu + ((v.u >> 16) & 1u)) >> 16;
  return (ushort)r;
}
__device__ __forceinline__ float bf2f(ushort u) {
  union { uint32_t u; float f; } v; v.u = ((uint32_t)u) << 16; return v.f;
}
// pack two f32 -> one u32 of 2 bf16 (lo = first arg); compiler emits v_cvt_pk_bf16_f32
__device__ __forceinline__ uint32_t pk2bf(float lo, float hi) {
  __hip_bfloat162 h = __float22bfloat162_rn({lo, hi});
  union { __hip_bfloat162 h; uint32_t u; } c; c.h = h; return c.u;
}

// global -> LDS direct copy, 16B per lane. LDS dest must be wave-uniform base.
__device__ __forceinline__ void gload_lds16(const void* g, void* l) {
  auto gp = (const __attribute__((address_space(1))) uint32_t*)(uintptr_t)g;
  auto lp = (__attribute__((address_space(3))) uint32_t*)(uint32_t)(uintptr_t)l;
  __builtin_amdgcn_global_load_lds(gp, lp, 16, 0, 0);
}

// exchange: swaps hi 32 lanes of a with lo 32 lanes of b
__device__ __forceinline__ void perm32swap(uint32_t& a, uint32_t& b) {
#if __has_builtin(__builtin_amdgcn_permlane32_swap)
  u32x2 r = __builtin_amdgcn_permlane32_swap(a, b, false, false);
  a = r[0]; b = r[1];
#else
  uint32_t sa = __shfl_xor((int)a, 32), sb = __shfl_xor((int)b, 32);
  bool lo = (threadIdx.x & 63) < 32;
  uint32_t na = lo ? a : sb;
  uint32_t nb = lo ? sa : b;
  a = na; b = nb;
#endif
}

// ---------------- K1a: per-block partial sum/sumsq over x (2M floats) -------
__global__ __launch_bounds__(256) void k_stats1(const float* __restrict__ x,
                                                float* __restrict__ part) {
  int t = threadIdx.x, b = blockIdx.x;
  float s = 0.f, ss = 0.f;
  const float4* x4 = (const float4*)x;
  for (int i = 0; i < 4; ++i) {
    float4 v = x4[(size_t)i * 131072 + b * 256 + t];
    s += v.x + v.y + v.z + v.w;
    ss += v.x * v.x + v.y * v.y + v.z * v.z + v.w * v.w;
  }
  for (int m = 1; m < 64; m <<= 1) { s += __shfl_xor(s, m); ss += __shfl_xor(ss, m); }
  __shared__ float ls[4], lss[4];
  int w = t >> 6, lane = t & 63;
  if (lane == 0) { ls[w] = s; lss[w] = ss; }
  __syncthreads();
  if (t == 0) {
    part[b * 2 + 0] = ls[0] + ls[1] + ls[2] + ls[3];
    part[b * 2 + 1] = lss[0] + lss[1] + lss[2] + lss[3];
  }
}

// ---------------- K1b: finalize mean / rsqrt(var+eps) ----------------------
__global__ __launch_bounds__(256) void k_stats2(const float* __restrict__ part,
                                                float* __restrict__ stat) {
  int t = threadIdx.x;
  float s = 0.f, ss = 0.f;
  for (int i = t; i < 512; i += 256) { s += part[i * 2]; ss += part[i * 2 + 1]; }
  for (int m = 1; m < 64; m <<= 1) { s += __shfl_xor(s, m); ss += __shfl_xor(ss, m); }
  __shared__ float ls[4], lss[4];
  int w = t >> 6, lane = t & 63;
  if (lane == 0) { ls[w] = s; lss[w] = ss; }
  __syncthreads();
  if (t == 0) {
    float sum = ls[0] + ls[1] + ls[2] + ls[3];
    float ssum = lss[0] + lss[1] + lss[2] + lss[3];
    float mean = sum * (1.f / 2097152.f);
    float var = ssum * (1.f / 2097152.f) - mean * mean;
    stat[0] = mean;
    stat[1] = rsqrtf(var + 1e-5f);
  }
}

// ---------------- K2a: cast weights to bf16 ---------------------------------
__global__ __launch_bounds__(256) void k_castw(const float* __restrict__ qw, const float* __restrict__ kw,
                                               const float* __restrict__ vw, const float* __restrict__ ow,
                                               ushort* __restrict__ wqkv, ushort* __restrict__ wo) {
  int idx = blockIdx.x * 256 + threadIdx.x;  // grid 1024 -> 262144
  if (idx < 65536) wqkv[idx] = f2bf(qw[idx]);
  else if (idx < 131072) wqkv[idx] = f2bf(kw[idx - 65536]);
  else if (idx < 196608) wqkv[idx] = f2bf(vw[idx - 131072]);
  else wo[idx - 196608] = f2bf(ow[idx - 196608]);
}

// ---------------- K2b: normalize + transpose -> xnT bf16 [8192][256] --------
__global__ __launch_bounds__(256) void k_norm_t(const float* __restrict__ x,
                                                const float* __restrict__ gw, const float* __restrict__ gb,
                                                const float* __restrict__ stat, ushort* __restrict__ xnT) {
  __shared__ float tile[64][66];
  int n0 = blockIdx.x * 64, c0 = blockIdx.y * 64;
  int t = threadIdx.x, colr = t & 63, rq = t >> 6;
  float mean = stat[0], rinv = stat[1];
  for (int rr = 0; rr < 16; ++rr) {
    int row = rr * 4 + rq;  // c-local
    int c = c0 + row;
    float v = x[(size_t)c * NSP + n0 + colr];
    tile[row][colr] = (v - mean) * rinv * gw[c] + gb[c];
  }
  __syncthreads();
  for (int rr = 0; rr < 16; ++rr) {
    int rowW = rr * 4 + rq;  // n-local
    xnT[(size_t)(n0 + rowW) * 256 + c0 + colr] = f2bf(tile[colr][rowW]);
  }
}

// ---------------- K3: QKV GEMM -> qT(scaled)/kT/vT [8192][256] bf16 ---------
__global__ __launch_bounds__(256) void k_qkv(const ushort* __restrict__ xnT, const ushort* __restrict__ wqkv,
                                             const float* __restrict__ qb, const float* __restrict__ kb,
                                             const float* __restrict__ vb,
                                             ushort* __restrict__ qT, ushort* __restrict__ kT,
                                             ushort* __restrict__ vT) {
  int nb = blockIdx.x, ob = blockIdx.y;
  int w = threadIdx.x >> 6, lane = threadIdx.x & 63;
  int l16 = lane & 15, kgrp = lane >> 4;
  int n_row = nb * 64 + w * 16 + l16;
  bf16x8 a[8];
  const bf16x8* arow = (const bf16x8*)(xnT + (size_t)n_row * 256);
  for (int ks = 0; ks < 8; ++ks) a[ks] = arow[ks * 4 + kgrp];
  f32x4 acc[4];
  for (int ct = 0; ct < 4; ++ct) {
    int o = ob * 64 + ct * 16 + l16;
    const bf16x8* brow = (const bf16x8*)(wqkv + (size_t)o * 256);
    f32x4 c = {0.f, 0.f, 0.f, 0.f};
    for (int ks = 0; ks < 8; ++ks)
      c = __builtin_amdgcn_mfma_f32_16x16x32_bf16(a[ks], brow[ks * 4 + kgrp], c, 0, 0, 0);
    acc[ct] = c;
  }
  const float SCALE = 0.0625f * 1.44269504088896340736f;  // (1/sqrt(C)) * log2(e)
  for (int ct = 0; ct < 4; ++ct) {
    int o = ob * 64 + ct * 16 + l16;
    for (int r = 0; r < 4; ++r) {
      int n = nb * 64 + w * 16 + kgrp * 4 + r;
      float v = acc[ct][r];
      if (o < 256) qT[(size_t)n * 256 + o] = f2bf((v + qb[o]) * SCALE);
      else if (o < 512) kT[(size_t)n * 256 + (o - 256)] = f2bf(v + kb[o - 256]);
      else vT[(size_t)n * 256 + (o - 512)] = f2bf(v + vb[o - 512]);
    }
  }
}

// ---------------- K4: transpose vT [8192][256] -> v_cm [256][8192] ----------
__global__ __launch_bounds__(256) void k_transv(const ushort* __restrict__ vT,
                                                ushort* __restrict__ v_cm) {
  __shared__ ushort tile[64][66];
  int n0 = blockIdx.x * 64, c0 = blockIdx.y * 64;
  int t = threadIdx.x, colr = t & 63, rq = t >> 6;
  for (int rr = 0; rr < 16; ++rr) {
    int row = rr * 4 + rq;  // n-local
    tile[row][colr] = vT[(size_t)(n0 + row) * 256 + c0 + colr];
  }
  __syncthreads();
  for (int rr = 0; rr < 16; ++rr) {
    int rowW = rr * 4 + rq;  // c-local
    v_cm[(size_t)(c0 + rowW) * NSP + n0 + colr] = tile[colr][rowW];
  }
}

// ---------------- K5a: flash attention, 32x32 MFMA, 2 blocks/CU -------------
// grid 512 = 2 blocks/CU (64 qblocks x 8 splits; split = bid&7 -> XCD affinity).
// Block: 256 threads (4 waves), wave owns 32 queries. LDS 64KB -> 2 blocks/CU,
// 2 waves/SIMD for latency hiding. VGPR capped at 256 via launch_bounds.
__global__ __launch_bounds__(256, 2) void k_attn(const ushort* __restrict__ qT, const ushort* __restrict__ kT,
                                                 const ushort* __restrict__ v_cm,
                                                 ushort* __restrict__ Opart, float* __restrict__ mpart,
                                                 float* __restrict__ lpart) {
  __shared__ __align__(16) ushort SMEM[32768];  // 64 KB
  ushort* k_lds = SMEM;          // 2 x 8192 ushorts: [32 key][256 c], 16B slots XOR-swz by key&7
  ushort* v_lds = SMEM + 16384;  // 2 x 8192 ushorts: [slot s<4][256 c][8 m], s covers m=s*8..s*8+7

  int bid = blockIdx.x;
  int split = bid & 7, qblk = bid >> 3;
  int t = threadIdx.x, w = t >> 6, lane = t & 63;
  int l31 = lane & 31, lhi = lane >> 5, l7 = lane & 7;
  int q0w = qblk * 128 + w * 32;

  // Q as B-operand fragments: lane holds q=l31, channels cs*16 + lhi*8 + j
  bf16x8 qf[16];
  {
    const char* qbase = (const char*)qT + (size_t)(q0w + l31) * 512;
#pragma unroll
    for (int cs = 0; cs < 16; ++cs)
      qf[cs] = *(const bf16x8*)(qbase + cs * 32 + lhi * 16);
  }

  f32x16 acc[8] = {};                 // O[c][q]: 8 blocks of 32 channels
  float m_r = -1e30f, l_p = 0.f;      // per-lane (query q = l31)

  const char* kT_b = (const char*)kT + (size_t)split * KEYS_PER_SPLIT * 512;
  const char* v_b = (const char*)v_cm + (size_t)split * KEYS_PER_SPLIT * 2;

  // stage tile tt (keys tt*32..+32) into buffer bsel: K 16KB + V 16KB, 8 loads/wave
  auto STAGE = [&](int tt, int bsel) {
    // K: wave w stages keys w*8..w*8+7; LDS[key][slot] = G[key][slot ^ (key&7)]
    const char* ksrc = kT_b + (size_t)tt * KBLK * 512;
    char* kdst = (char*)(k_lds + bsel * 8192) + w * 4096;
#pragma unroll
    for (int i = 0; i < 4; ++i) {
      int keyloc = w * 8 + i * 2 + lhi;
      int srcoff = keyloc * 512 + ((l31 ^ (keyloc & 7)) << 4);
      gload_lds16(ksrc + srcoff, kdst + i * 1024);
    }
    // V: wave w stages slot w (m = w*8..w*8+7); linear, conflict-free by construction
    char* vdst = (char*)(v_lds + bsel * 8192) + w * 4096;
    const char* vsrc = v_b + (size_t)tt * 64 + w * 16;
#pragma unroll
    for (int i = 0; i < 4; ++i) {
      int c = i * 64 + lane;
      gload_lds16(vsrc + (size_t)c * 16384, vdst + i * 1024);
    }
  };

  STAGE(0, 0);  // prologue

#pragma unroll 1
  for (int tt = 0; tt < NTILES; ++tt) {
    int cur = tt & 1;
    if (tt + 1 < NTILES) {
      STAGE(tt + 1, cur ^ 1);
      asm volatile("s_waitcnt vmcnt(8)" ::: "memory");  // tile tt's 8 loads done
    } else {
      asm volatile("s_waitcnt vmcnt(0)" ::: "memory");
    }
    __builtin_amdgcn_s_barrier();

    // ---- QK^T: S[32 key][32 q] ----
    const ushort* kl = k_lds + cur * 8192;
    f32x16 S0 = {};
    __builtin_amdgcn_s_setprio(1);
#pragma unroll
    for (int cs = 0; cs < 16; ++cs) {
      int slot = (cs * 2 + lhi) ^ l7;
      bf16x8 a0 = *(const bf16x8*)(kl + l31 * 256 + slot * 8);
      S0 = __builtin_amdgcn_mfma_f32_32x32x16_bf16(a0, qf[cs], S0, 0, 0, 0);
    }
    __builtin_amdgcn_s_setprio(0);

    // ---- online softmax, in-register (lane owns q=l31; partner lane^32 has other 16 keys)
    float pm = S0[0];
#pragma unroll
    for (int r = 1; r < 16; ++r) pm = fmaxf(pm, S0[r]);
    pm = fmaxf(pm, __shfl_xor(pm, 32));
    if (!__all(pm <= m_r + 8.f)) {   // defer-max slow path (rare)
      float mn = fmaxf(m_r, pm);
      float alpha = __builtin_amdgcn_exp2f(m_r - mn);
      m_r = mn;
      l_p *= alpha;
#pragma unroll
      for (int cb = 0; cb < 8; ++cb)
#pragma unroll
        for (int r = 0; r < 16; ++r) acc[cb][r] *= alpha;
    }
    {
      float t0 = 0.f, t1 = 0.f, t2 = 0.f, t3 = 0.f;
#pragma unroll
      for (int r = 0; r < 16; ++r) {
        S0[r] = __builtin_amdgcn_exp2f(S0[r] - m_r);
        if (r < 4) t0 += S0[r];
        else if (r < 8) t1 += S0[r];
        else if (r < 12) t2 += S0[r];
        else t3 += S0[r];
      }
      l_p += (t0 + t1) + (t2 + t3);
    }

    // ---- P -> bf16 B-fragments via cvt_pk + permlane32_swap ----
    bf16x8 pf[2];
    {
      union { uint32_t w[4]; bf16x8 v; } u;
#pragma unroll
      for (int h = 0; h < 2; ++h) {
        int b = h * 8;
        uint32_t x = pk2bf(S0[b + 0], S0[b + 1]), y = pk2bf(S0[b + 4], S0[b + 5]);
        perm32swap(x, y);
        uint32_t x2 = pk2bf(S0[b + 2], S0[b + 3]), y2 = pk2bf(S0[b + 6], S0[b + 7]);
        perm32swap(x2, y2);
        u.w[0] = x; u.w[1] = x2; u.w[2] = y; u.w[3] = y2;
        pf[h] = u.v;
      }
    }

    // ---- PV: O[c][q] += V^T[c][m] P[m][q] ----
    const ushort* vl = v_lds + cur * 8192;
    __builtin_amdgcn_s_setprio(1);
#pragma unroll
    for (int cb = 0; cb < 8; ++cb) {
#pragma unroll
      for (int h = 0; h < 2; ++h) {
        int s = h * 2 + lhi;
        bf16x8 a = *(const bf16x8*)(vl + s * 2048 + (cb * 32 + l31) * 8);
        acc[cb] = __builtin_amdgcn_mfma_f32_32x32x16_bf16(a, pf[h], acc[cb], 0, 0, 0);
      }
    }
    __builtin_amdgcn_s_setprio(0);
    asm volatile("s_waitcnt lgkmcnt(0)" ::: "memory");
    __builtin_amdgcn_s_barrier();  // all waves done reading buf[cur]
  }

  // ---- epilogue: l reduce, O -> LDS transpose (chunked) -> coalesced store ----
  float l_tot = l_p + __shfl_xor(l_p, 32);

  // per-wave scratch: 32 q-rows x 272B (128 c x 2B + 16B pad); 4 waves = 34KB < 64KB
  char* eb = (char*)SMEM + w * 8704;
  size_t gq0 = (size_t)split * NSP + q0w;
#pragma unroll
  for (int ch = 0; ch < 2; ++ch) {
#pragma unroll
    for (int cb4 = 0; cb4 < 4; ++cb4) {
      int cb = ch * 4 + cb4;
#pragma unroll
      for (int g = 0; g < 4; ++g) {
        int cl = cb4 * 32 + g * 8 + 4 * lhi;
        *(uint32_t*)(eb + l31 * 272 + cl * 2) = pk2bf(acc[cb][g * 4 + 0], acc[cb][g * 4 + 1]);
        *(uint32_t*)(eb + l31 * 272 + cl * 2 + 4) = pk2bf(acc[cb][g * 4 + 2], acc[cb][g * 4 + 3]);
      }
    }
#pragma unroll
    for (int i = 0; i < 8; ++i) {
      int flat = i * 1024 + lane * 16;
      int qr = flat >> 8, off = flat & 255;
      uint4 val = *(const uint4*)(eb + qr * 272 + off);
      *(uint4*)((char*)Opart + (gq0 + qr) * 512 + ch * 256 + off) = val;
    }
  }
  if (lane < 32) {
    int q = q0w + l31;
    mpart[split * NSP + q] = m_r;
    lpart[split * NSP + q] = l_tot;
  }
}

// ---------------- K5b: combine split partials -> attT bf16 [8192][256] ------
__global__ __launch_bounds__(256) void k_combine(const ushort* __restrict__ Opart,
                                                 const float* __restrict__ mpart,
                                                 const float* __restrict__ lpart,
                                                 ushort* __restrict__ attT) {
  int q = blockIdx.x;
  int c = threadIdx.x;
  float m[NSPLIT], l[NSPLIT];
  float M = -1e30f;
  for (int s = 0; s < NSPLIT; ++s) {
    m[s] = mpart[s * NSP + q];
    l[s] = lpart[s * NSP + q];
    M = fmaxf(M, m[s]);
  }
  float L = 0.f, acc = 0.f;
  for (int s = 0; s < NSPLIT; ++s) {
    float ws = __builtin_amdgcn_exp2f(m[s] - M);
    L += ws * l[s];
    acc += ws * bf2f(Opart[((size_t)s * NSP + q) * 256 + c]);
  }
  attT[(size_t)q * 256 + c] = f2bf(acc / L);
}

// ---------------- K6: out = xn + ow @ att + ob ------------------------------
__global__ __launch_bounds__(256) void k_final(const ushort* __restrict__ attT, const ushort* __restrict__ wo,
                                               const float* __restrict__ ob, const float* __restrict__ x,
                                               const float* __restrict__ gw, const float* __restrict__ gb,
                                               const float* __restrict__ stat, float* __restrict__ out) {
  int nb = blockIdx.x, obk = blockIdx.y;
  int w = threadIdx.x >> 6, lane = threadIdx.x & 63;
  int l16 = lane & 15, kgrp = lane >> 4;
  int orow = obk * 64 + w * 16 + l16;
  bf16x8 a[8];
  const bf16x8* arow = (const bf16x8*)(wo + (size_t)orow * 256);
  for (int ks = 0; ks < 8; ++ks) a[ks] = arow[ks * 4 + kgrp];
  float mean = stat[0], rinv = stat[1];
  f32x4 acc[4];
  for (int ct = 0; ct < 4; ++ct) {
    int n = nb * 64 + ct * 16 + l16;
    const bf16x8* brow = (const bf16x8*)(attT + (size_t)n * 256);
    f32x4 c = {0.f, 0.f, 0.f, 0.f};
    for (int ks = 0; ks < 8; ++ks)
      c = __builtin_amdgcn_mfma_f32_16x16x32_bf16(a[ks], brow[ks * 4 + kgrp], c, 0, 0, 0);
    acc[ct] = c;
  }
  for (int ct = 0; ct < 4; ++ct) {
    for (int r = 0; r < 4; ++r) {
      int o = obk * 64 + w * 16 + kgrp * 4 + r;
      int n = nb * 64 + ct * 16 + l16;
      float xv = x[(size_t)o * NSP + n];
      float xn = (xv - mean) * rinv * gw[o] + gb[o];
      out[(size_t)o * NSP + n] = xn + acc[ct][r] + ob[o];
    }
  }
}

extern "C" void kernel_launch(void* const* d_in, const int* in_sizes, int n_in,
                              void* d_out, int out_size, void* d_ws, size_t ws_size,
                              hipStream_t stream) {
  const float* x = (const float*)d_in[0];
  const float* gw = (const float*)d_in[1];
  const float* gb = (const float*)d_in[2];
  const float* qw = (const float*)d_in[3];
  const float* qbv = (const float*)d_in[4];
  const float* kw = (const float*)d_in[5];
  const float* kbv = (const float*)d_in[6];
  const float* vw = (const float*)d_in[7];
  const float* vbv = (const float*)d_in[8];
  const float* ow = (const float*)d_in[9];
  const float* obv = (const float*)d_in[10];
  float* out = (float*)d_out;
  char* ws = (char*)d_ws;
  const size_t KB = 1024, MB = 1048576;
  // region plan (high-water 49 MB):
  //  0..4KB      part
  //  60KB        stat
  //  64..448KB   wqkv (dead after k_qkv)
  //  448..576KB  wo
  //  1..5MB      xnT (k_norm_t->k_qkv) -> v_cm (k_transv->k_attn) -> attT (k_combine->k_final)
  //  5..9MB      qT
  //  9..13MB     kT
  //  13..17MB    vT (dead after k_transv) -> mpart/lpart (k_attn+)
  //  17..49MB    Opart (8 splits, bf16)
  float* part = (float*)(ws);
  float* stat = (float*)(ws + 60 * KB);
  ushort* wqkv = (ushort*)(ws + 64 * KB);
  ushort* wo = (ushort*)(ws + 448 * KB);
  ushort* xnT = (ushort*)(ws + 1 * MB);
  ushort* qT = (ushort*)(ws + 5 * MB);
  ushort* kT = (ushort*)(ws + 9 * MB);
  ushort* vT = (ushort*)(ws + 13 * MB);
  ushort* v_cm = xnT;   // alias: xnT dead after k_qkv
  ushort* attT = xnT;   // alias: v_cm dead after k_attn
  float* mpart = (float*)(ws + 13 * MB);            // overlays dead vT
  float* lpart = (float*)(ws + 13 * MB + 256 * KB);
  ushort* Opart = (ushort*)(ws + 17 * MB);          // 32 MB

  k_stats1<<<512, 256, 0, stream>>>(x, part);
  k_stats2<<<1, 256, 0, stream>>>(part, stat);
  k_castw<<<1024, 256, 0, stream>>>(qw, kw, vw, ow, wqkv, wo);
  k_norm_t<<<dim3(128, 4), 256, 0, stream>>>(x, gw, gb, stat, xnT);
  k_qkv<<<dim3(128, 12), 256, 0, stream>>>(xnT, wqkv, qbv, kbv, vbv, qT, kT, vT);
  k_transv<<<dim3(128, 4), 256, 0, stream>>>(vT, v_cm);
  k_attn<<<512, 256, 0, stream>>>(qT, kT, v_cm, Opart, mpart, lpart);
  k_combine<<<NSP, 256, 0, stream>>>(Opart, mpart, lpart, attT);
  k_final<<<dim3(128, 4), 256, 0, stream>>>(attT, wo, obv, x, gw, gb, stat, out);
}